// Round 1
// baseline (117.782 us; speedup 1.0000x reference)
//
#include <hip/hip_runtime.h>
#include <hip/hip_bf16.h>

// B=8, N=128, M=256, E=256, De=64, H=8, D=32
#define B_ 8
#define N_ 128
#define M_ 256
#define E_ 256
#define De_ 64
#define H_ 8
#define D_ 32
#define INV_SCALE 0.17677669529663687f
#define LN_EPS 1e-5f

// ---------------- Kernel 1: Q/K/V projections ----------------
// out[r][e] = sum_j in[r][j] * w[e][j]   (torch Linear: x @ W.T)
// RPB = 8 rows per block, 256 threads (thread = output col e).
__global__ __launch_bounds__(256) void proj3_kernel(
    const float* __restrict__ q, const float* __restrict__ k, const float* __restrict__ v,
    const float* __restrict__ wq, const float* __restrict__ wk, const float* __restrict__ wv,
    float* __restrict__ Qp, float* __restrict__ Kp, float* __restrict__ Vp) {
  constexpr int RPB = 8;
  __shared__ float in_s[RPB][E_];
  int blk = blockIdx.x;
  const float* in; const float* w; float* out; int r0;
  if (blk < 128)      { in = q; w = wq; out = Qp; r0 = blk * RPB; }
  else if (blk < 384) { in = k; w = wk; out = Kp; r0 = (blk - 128) * RPB; }
  else                { in = v; w = wv; out = Vp; r0 = (blk - 384) * RPB; }
  int t = threadIdx.x;
  #pragma unroll
  for (int r = 0; r < RPB; ++r) in_s[r][t] = in[(r0 + r) * E_ + t];
  __syncthreads();
  float acc[RPB];
  #pragma unroll
  for (int r = 0; r < RPB; ++r) acc[r] = 0.f;
  const float4* wrow = reinterpret_cast<const float4*>(w + (size_t)t * E_);
  for (int j4 = 0; j4 < E_ / 4; ++j4) {
    float4 wv4 = wrow[j4];
    #pragma unroll
    for (int r = 0; r < RPB; ++r) {
      float4 iv = *reinterpret_cast<const float4*>(&in_s[r][j4 * 4]);
      acc[r] += wv4.x * iv.x + wv4.y * iv.y + wv4.z * iv.z + wv4.w * iv.w;
    }
  }
  #pragma unroll
  for (int r = 0; r < RPB; ++r) out[(size_t)(r0 + r) * E_ + t] = acc[r];
}

// ---------------- Kernel 2: fused edge-aware attention ----------------
// One block per (b,n). 256 threads.
__global__ __launch_bounds__(256) void attn_kernel(
    const float* __restrict__ Qp, const float* __restrict__ Kp, const float* __restrict__ Vp,
    const float* __restrict__ edge, const float* __restrict__ ep_w, const float* __restrict__ ep_b,
    float* __restrict__ ctx) {
  __shared__ float edge_s[M_ * 65];     // [m][de] padded 64->65 (bank-conflict fix)
  __shared__ float qrow[E_];
  __shared__ float qep_s[H_ * De_];     // [h][de]
  __shared__ float qb_s[H_];
  __shared__ float attn_s[H_ * M_];     // [h][m] (raw scores, then exp)
  __shared__ float rsum_s[H_];
  __shared__ float attnE_s[H_ * De_];   // [h][de]

  int bn = blockIdx.x;            // 0..1023
  int b = bn >> 7;
  int t = threadIdx.x;

  // ---- stage Q row + edge slice ----
  qrow[t] = Qp[(size_t)bn * E_ + t];
  const float4* esrc = reinterpret_cast<const float4*>(edge + (size_t)bn * (M_ * De_));
  #pragma unroll
  for (int it = 0; it < 16; ++it) {
    int idx4 = it * 256 + t;            // float4 index within slice
    float4 ev = esrc[idx4];
    int flat = idx4 * 4;
    int m = flat >> 6, de = flat & 63;
    float* dst = &edge_s[m * 65 + de];
    dst[0] = ev.x; dst[1] = ev.y; dst[2] = ev.z; dst[3] = ev.w;
  }
  __syncthreads();

  // ---- qep[h][de] = sum_d Q[h*32+d] * ep_w[h*32+d][de];  qb[h] = sum_d Q*ep_b ----
  #pragma unroll
  for (int rep = 0; rep < 2; ++rep) {
    int e2 = t + rep * 256;
    int h = e2 >> 6, de = e2 & 63;
    float s = 0.f;
    #pragma unroll
    for (int d = 0; d < D_; ++d)
      s += qrow[h * D_ + d] * ep_w[(size_t)(h * D_ + d) * De_ + de];
    qep_s[e2] = s;
  }
  if (t < H_) {
    float s = 0.f;
    #pragma unroll
    for (int d = 0; d < D_; ++d) s += qrow[t * D_ + d] * ep_b[t * D_ + d];
    qb_s[t] = s;
  }
  __syncthreads();

  // ---- scores: thread t = m, loop heads ----
  {
    const int m = t;
    const float* krow = Kp + ((size_t)b * M_ + m) * E_;
    #pragma unroll
    for (int h = 0; h < H_; ++h) {
      float s = 0.f;
      #pragma unroll
      for (int d4 = 0; d4 < D_ / 4; ++d4) {
        float4 kv = *reinterpret_cast<const float4*>(krow + h * D_ + d4 * 4);
        float4 qv = *reinterpret_cast<const float4*>(&qrow[h * D_ + d4 * 4]);
        s += kv.x * qv.x + kv.y * qv.y + kv.z * qv.z + kv.w * qv.w;
      }
      float se = 0.f;
      #pragma unroll
      for (int de = 0; de < De_; ++de)
        se += edge_s[m * 65 + de] * qep_s[h * De_ + de];
      attn_s[h * M_ + m] = (s + se + qb_s[h]) * INV_SCALE;
    }
  }
  __syncthreads();

  // ---- softmax: 32-lane group per head ----
  {
    int g = t >> 5, l = t & 31;
    float mx = -1e30f;
    #pragma unroll
    for (int kk = 0; kk < 8; ++kk) mx = fmaxf(mx, attn_s[g * M_ + l + kk * 32]);
    #pragma unroll
    for (int ofs = 16; ofs; ofs >>= 1) mx = fmaxf(mx, __shfl_xor(mx, ofs));
    float sum = 0.f;
    #pragma unroll
    for (int kk = 0; kk < 8; ++kk) {
      float e = __expf(attn_s[g * M_ + l + kk * 32] - mx);
      attn_s[g * M_ + l + kk * 32] = e;
      sum += e;
    }
    #pragma unroll
    for (int ofs = 16; ofs; ofs >>= 1) sum += __shfl_xor(sum, ofs);
    if (l == 0) rsum_s[g] = 1.f / sum;
  }
  __syncthreads();

  // ---- ctxV (thread = (h,d)) and attnE (thread = 2x (h,de)) ----
  float ctxv;
  {
    int h = t >> 5, d = t & 31;
    float acc = 0.f;
    const float* vcol = Vp + (size_t)b * M_ * E_ + h * D_ + d;
    for (int m = 0; m < M_; ++m)
      acc += attn_s[h * M_ + m] * vcol[(size_t)m * E_];
    ctxv = acc * rsum_s[h];
  }
  #pragma unroll
  for (int rep = 0; rep < 2; ++rep) {
    int e2 = t + rep * 256;
    int h = e2 >> 6, de = e2 & 63;
    float acc = 0.f;
    for (int m = 0; m < M_; ++m)
      acc += attn_s[h * M_ + m] * edge_s[m * 65 + de];
    attnE_s[e2] = acc * rsum_s[h];
  }
  __syncthreads();

  // ---- ctx_edge through ep_w, combine, write ----
  {
    int h = t >> 5, d = t & 31;
    int e = h * D_ + d;
    float acc = 0.f;
    #pragma unroll
    for (int de = 0; de < De_; ++de)
      acc += attnE_s[h * De_ + de] * ep_w[(size_t)e * De_ + de];
    ctx[(size_t)bn * E_ + t] = ctxv + acc + ep_b[e];
  }
}

// ---------------- Kernel 3: output proj + residual + LayerNorm ----------------
__global__ __launch_bounds__(256) void out_ln_kernel(
    const float* __restrict__ ctx, const float* __restrict__ wo_w,
    const float* __restrict__ wo_b, const float* __restrict__ qin,
    const float* __restrict__ ln_g, const float* __restrict__ ln_b,
    float* __restrict__ out) {
  constexpr int RPB = 4;
  __shared__ float ctx_s[RPB][E_];
  __shared__ float o_s[RPB][E_];
  int r0 = blockIdx.x * RPB;
  int t = threadIdx.x;
  #pragma unroll
  for (int r = 0; r < RPB; ++r) ctx_s[r][t] = ctx[(size_t)(r0 + r) * E_ + t];
  __syncthreads();
  float acc[RPB];
  #pragma unroll
  for (int r = 0; r < RPB; ++r) acc[r] = 0.f;
  const float4* wrow = reinterpret_cast<const float4*>(wo_w + (size_t)t * E_);
  for (int j4 = 0; j4 < E_ / 4; ++j4) {
    float4 wv4 = wrow[j4];
    #pragma unroll
    for (int r = 0; r < RPB; ++r) {
      float4 iv = *reinterpret_cast<const float4*>(&ctx_s[r][j4 * 4]);
      acc[r] += wv4.x * iv.x + wv4.y * iv.y + wv4.z * iv.z + wv4.w * iv.w;
    }
  }
  float bias = wo_b[t];
  #pragma unroll
  for (int r = 0; r < RPB; ++r)
    o_s[r][t] = acc[r] + bias + qin[(size_t)(r0 + r) * E_ + t];
  __syncthreads();
  // LayerNorm: one 64-lane wave per row
  int r = t >> 6;
  int lane = t & 63;
  float sum = 0.f, sq = 0.f;
  #pragma unroll
  for (int kk = 0; kk < 4; ++kk) {
    float x = o_s[r][lane + kk * 64];
    sum += x; sq += x * x;
  }
  #pragma unroll
  for (int ofs = 32; ofs; ofs >>= 1) {
    sum += __shfl_xor(sum, ofs);
    sq  += __shfl_xor(sq, ofs);
  }
  float mu = sum * (1.f / E_);
  float var = sq * (1.f / E_) - mu * mu;
  float rstd = rsqrtf(var + LN_EPS);
  #pragma unroll
  for (int kk = 0; kk < 4; ++kk) {
    int e = lane + kk * 64;
    float x = o_s[r][e];
    out[(size_t)(r0 + r) * E_ + e] = (x - mu) * rstd * ln_g[e] + ln_b[e];
  }
}

extern "C" void kernel_launch(void* const* d_in, const int* in_sizes, int n_in,
                              void* d_out, int out_size, void* d_ws, size_t ws_size,
                              hipStream_t stream) {
  const float* q    = (const float*)d_in[0];
  const float* k    = (const float*)d_in[1];
  const float* v    = (const float*)d_in[2];
  const float* edge = (const float*)d_in[3];
  const float* wq   = (const float*)d_in[4];
  const float* wk   = (const float*)d_in[5];
  const float* wv   = (const float*)d_in[6];
  const float* wo_w = (const float*)d_in[7];
  const float* wo_b = (const float*)d_in[8];
  const float* ep_w = (const float*)d_in[9];
  const float* ep_b = (const float*)d_in[10];
  const float* ln_g = (const float*)d_in[11];
  const float* ln_b = (const float*)d_in[12];
  float* out = (float*)d_out;

  float* Qp  = (float*)d_ws;                      // [B*N, E]   1 MB
  float* Kp  = Qp + (size_t)B_ * N_ * E_;         // [B*M, E]   2 MB
  float* Vp  = Kp + (size_t)B_ * M_ * E_;         // [B*M, E]   2 MB
  float* ctx = Vp + (size_t)B_ * M_ * E_;         // [B*N, E]   1 MB

  proj3_kernel<<<640, 256, 0, stream>>>(q, k, v, wq, wk, wv, Qp, Kp, Vp);
  attn_kernel<<<B_ * N_, 256, 0, stream>>>(Qp, Kp, Vp, edge, ep_w, ep_b, ctx);
  out_ln_kernel<<<B_ * N_ / 4, 256, 0, stream>>>(ctx, wo_w, wo_b, q, ln_g, ln_b, out);
}